// Round 1
// baseline (764.640 us; speedup 1.0000x reference)
//
#include <hip/hip_runtime.h>

#define D 128
#define NHEAD 4
#define DH 32

// ---------------- CSR build ----------------

__global__ __launch_bounds__(256) void hist_kernel(const int* __restrict__ dst,
                                                   int* __restrict__ deg, int E) {
  int i = blockIdx.x * blockDim.x + threadIdx.x;
  int stride = gridDim.x * blockDim.x;
  for (int e = i; e < E; e += stride) atomicAdd(&deg[dst[e]], 1);
}

// single-block exclusive scan over n counters -> off[0..n], cursor copy
__global__ __launch_bounds__(1024) void scan_kernel(const int* __restrict__ deg,
                                                    int* __restrict__ off,
                                                    int* __restrict__ cur, int n) {
  __shared__ int wsum[16];
  const int lane = threadIdx.x & 63;
  const int wid = threadIdx.x >> 6;
  int carry = 0;
  for (int base = 0; base < n; base += 1024) {
    int i = base + (int)threadIdx.x;
    int v = (i < n) ? deg[i] : 0;
    int s = v;
#pragma unroll
    for (int d = 1; d < 64; d <<= 1) {
      int t = __shfl_up(s, d);
      if (lane >= d) s += t;
    }
    if (lane == 63) wsum[wid] = s;
    __syncthreads();
    if (wid == 0) {
      int ws = (lane < 16) ? wsum[lane] : 0;
#pragma unroll
      for (int d = 1; d < 16; d <<= 1) {
        int t = __shfl_up(ws, d);
        if (lane >= d) ws += t;
      }
      if (lane < 16) wsum[lane] = ws;
    }
    __syncthreads();
    int wave_excl = wid ? wsum[wid - 1] : 0;
    int excl = carry + wave_excl + (s - v);
    if (i < n) { off[i] = excl; cur[i] = excl; }
    carry += wsum[15];
    __syncthreads();
  }
  if (threadIdx.x == 0) off[n] = carry;
}

__global__ __launch_bounds__(256) void scatter_kernel(const int* __restrict__ src,
                                                      const int* __restrict__ dst,
                                                      int* __restrict__ cur,
                                                      int* __restrict__ csr, int E) {
  int i = blockIdx.x * blockDim.x + threadIdx.x;
  int stride = gridDim.x * blockDim.x;
  for (int e = i; e < E; e += stride) {
    int p = atomicAdd(&cur[dst[e]], 1);
    csr[p] = src[e];
  }
}

// ---------------- fused Q/K/V/Skip GEMM (f32 vector) ----------------
// grid.x = row tiles of 64, grid.y = matrix id (0=Q,1=K,2=V,3=S)

__global__ __launch_bounds__(256) void qkvs_gemm(
    const float* __restrict__ xin,
    const float* __restrict__ w0, const float* __restrict__ b0,
    const float* __restrict__ w1, const float* __restrict__ b1,
    const float* __restrict__ w2, const float* __restrict__ b2,
    const float* __restrict__ w3, const float* __restrict__ b3,
    float* __restrict__ Q, float* __restrict__ K, float* __restrict__ V,
    float* __restrict__ S, int n) {
  const int mat = blockIdx.y;
  const float* wm; const float* bm; float* om;
  switch (mat) {
    case 0: wm = w0; bm = b0; om = Q; break;
    case 1: wm = w1; bm = b1; om = K; break;
    case 2: wm = w2; bm = b2; om = V; break;
    default: wm = w3; bm = b3; om = S; break;
  }
  __shared__ float xs[64][132];  // pad 128->132: conflict-free column reads
  const int row0 = blockIdx.x * 64;
  for (int i = threadIdx.x; i < 64 * 32; i += 256) {
    int r = i >> 5, c4 = (i & 31) << 2;
    int gr = row0 + r;
    float4 v4 = make_float4(0.f, 0.f, 0.f, 0.f);
    if (gr < n) v4 = *(const float4*)(xin + (size_t)gr * D + c4);
    *(float4*)&xs[r][c4] = v4;
  }
  __syncthreads();

  const int ty = threadIdx.x >> 4;   // 0..15 row group
  const int tx = threadIdx.x & 15;   // 0..15 col group
  const int ty4 = ty * 4;
  const int c0 = tx * 8;
  float acc[4][8];
#pragma unroll
  for (int i = 0; i < 4; i++)
#pragma unroll
    for (int j = 0; j < 8; j++) acc[i][j] = 0.f;

#pragma unroll 8
  for (int k = 0; k < D; ++k) {
    float4 bA = *(const float4*)(wm + k * D + c0);
    float4 bB = *(const float4*)(wm + k * D + c0 + 4);
    float b[8] = {bA.x, bA.y, bA.z, bA.w, bB.x, bB.y, bB.z, bB.w};
    float a[4];
    a[0] = xs[ty4 + 0][k];
    a[1] = xs[ty4 + 1][k];
    a[2] = xs[ty4 + 2][k];
    a[3] = xs[ty4 + 3][k];
#pragma unroll
    for (int i = 0; i < 4; i++)
#pragma unroll
      for (int j = 0; j < 8; j++) acc[i][j] = fmaf(a[i], b[j], acc[i][j]);
  }

  float4 bb0 = *(const float4*)(bm + c0);
  float4 bb1 = *(const float4*)(bm + c0 + 4);
#pragma unroll
  for (int i = 0; i < 4; i++) {
    int gr = row0 + ty4 + i;
    if (gr < n) {
      float4 o0 = make_float4(acc[i][0] + bb0.x, acc[i][1] + bb0.y,
                              acc[i][2] + bb0.z, acc[i][3] + bb0.w);
      float4 o1 = make_float4(acc[i][4] + bb1.x, acc[i][5] + bb1.y,
                              acc[i][6] + bb1.z, acc[i][7] + bb1.w);
      *(float4*)(om + (size_t)gr * D + c0) = o0;
      *(float4*)(om + (size_t)gr * D + c0 + 4) = o1;
    }
  }
}

// ---------------- per-node edge attention ----------------
// 256 threads = 2 nodes/block; within a node: 128 threads = (head h = t>>5, d = t&31)

__global__ __launch_bounds__(256) void attn_edge(
    const int* __restrict__ off, const int* __restrict__ csr,
    const float* __restrict__ Q, const float* __restrict__ K,
    const float* __restrict__ V, const float* __restrict__ S,
    float* __restrict__ outbuf, int n, int do_relu) {
  const int node = blockIdx.x * 2 + (threadIdx.x >> 7);
  if (node >= n) return;
  const int t = threadIdx.x & 127;
  const int e0 = off[node];
  const int e1 = off[node + 1];
  const float qv = Q[(size_t)node * D + t];
  const float scale = 0.17677669529663689f;  // 1/sqrt(32)

  float m = -1e30f, s = 0.f, acc = 0.f;
  int srcN = (e0 < e1) ? csr[e0] : 0;
  for (int e = e0; e < e1; ++e) {
    int src = srcN;
    if (e + 1 < e1) srcN = csr[e + 1];
    float kv = K[(size_t)src * D + t];
    float vv = V[(size_t)src * D + t];
    float p = qv * kv;
    // reduce over the 32 lanes of this head group
    p += __shfl_xor(p, 1);
    p += __shfl_xor(p, 2);
    p += __shfl_xor(p, 4);
    p += __shfl_xor(p, 8);
    p += __shfl_xor(p, 16);
    float logit = p * scale;
    float mn = fmaxf(m, logit);
    float c = __expf(m - mn);
    float w = __expf(logit - mn);
    s = s * c + w;
    acc = acc * c + w * vv;
    m = mn;
  }
  float attn = acc / (s + 1e-16f);
  float res = S[(size_t)node * D + t] + attn;
  if (do_relu) res = fmaxf(res, 0.f);
  outbuf[(size_t)node * D + t] = res;
}

// ---------------- launch ----------------

extern "C" void kernel_launch(void* const* d_in, const int* in_sizes, int n_in,
                              void* d_out, int out_size, void* d_ws, size_t ws_size,
                              hipStream_t stream) {
  const int N = in_sizes[0] / D;
  const int E = in_sizes[1] / 2;
  const float* x = (const float*)d_in[0];
  const int* ei = (const int*)d_in[1];
  const int* esrc = ei;
  const int* edst = ei + E;

  const float* qw0 = (const float*)d_in[2];  const float* qb0 = (const float*)d_in[3];
  const float* kw0 = (const float*)d_in[4];  const float* kb0 = (const float*)d_in[5];
  const float* vw0 = (const float*)d_in[6];  const float* vb0 = (const float*)d_in[7];
  const float* sw0 = (const float*)d_in[8];  const float* sb0 = (const float*)d_in[9];
  const float* qw1 = (const float*)d_in[10]; const float* qb1 = (const float*)d_in[11];
  const float* kw1 = (const float*)d_in[12]; const float* kb1 = (const float*)d_in[13];
  const float* vw1 = (const float*)d_in[14]; const float* vb1 = (const float*)d_in[15];
  const float* sw1 = (const float*)d_in[16]; const float* sb1 = (const float*)d_in[17];

  float* out = (float*)d_out;

  char* p = (char*)d_ws;
  auto carve = [&](size_t bytes) -> void* {
    void* r = (void*)p;
    p += (bytes + 255) & ~(size_t)255;
    return r;
  };
  int* deg = (int*)carve((size_t)N * 4);
  int* off = (int*)carve((size_t)(N + 1) * 4);
  int* cur = (int*)carve((size_t)N * 4);
  int* csr = (int*)carve((size_t)E * 4);
  float* Qb = (float*)carve((size_t)N * D * 4);
  float* Kb = (float*)carve((size_t)N * D * 4);
  float* Vb = (float*)carve((size_t)N * D * 4);
  float* h1 = (float*)carve((size_t)N * D * 4);

  hipMemsetAsync(deg, 0, (size_t)N * 4, stream);
  int eblocks = (E + 255) / 256;
  hist_kernel<<<eblocks, 256, 0, stream>>>(edst, deg, E);
  scan_kernel<<<1, 1024, 0, stream>>>(deg, off, cur, N);
  scatter_kernel<<<eblocks, 256, 0, stream>>>(esrc, edst, cur, csr, E);

  dim3 ggrid((N + 63) / 64, 4);
  int agrid = (N + 1) / 2;

  // layer 1: skip written into h1, attention added in-place, ReLU fused
  qkvs_gemm<<<ggrid, 256, 0, stream>>>(x, qw0, qb0, kw0, kb0, vw0, vb0, sw0, sb0,
                                       Qb, Kb, Vb, h1, N);
  attn_edge<<<agrid, 256, 0, stream>>>(off, csr, Qb, Kb, Vb, h1, h1, N, 1);

  // layer 2: skip written into d_out, attention added in-place, no ReLU
  qkvs_gemm<<<ggrid, 256, 0, stream>>>(h1, qw1, qb1, kw1, kb1, vw1, vb1, sw1, sb1,
                                       Qb, Kb, Vb, out, N);
  attn_edge<<<agrid, 256, 0, stream>>>(off, csr, Qb, Kb, Vb, out, out, N, 0);
}

// Round 2
// 484.497 us; speedup vs baseline: 1.5782x; 1.5782x over previous
//
#include <hip/hip_runtime.h>

#define D 128
#define NHEAD 4
#define DH 32

typedef unsigned short ushort_t;
typedef unsigned int uint_t;
typedef short bf16x8 __attribute__((ext_vector_type(8)));
typedef float f32x4 __attribute__((ext_vector_type(4)));

__device__ inline float bf2f_lo(uint_t u) {
  union { uint_t i; float f; } x; x.i = u << 16; return x.f;
}
__device__ inline float bf2f_hi(uint_t u) {
  union { uint_t i; float f; } x; x.i = u & 0xffff0000u; return x.f;
}
__device__ inline ushort_t f2bf(float f) {
  union { float f; uint_t u; } x; x.f = f;
  return (ushort_t)((x.u + 0x7fffu + ((x.u >> 16) & 1u)) >> 16);
}

// ---------------- CSR build ----------------

__global__ __launch_bounds__(256) void hist_kernel(const int* __restrict__ dst,
                                                   int* __restrict__ deg, int E) {
  int i = blockIdx.x * blockDim.x + threadIdx.x;
  int stride = gridDim.x * blockDim.x;
  for (int e = i; e < E; e += stride) atomicAdd(&deg[dst[e]], 1);
}

// 256 thr x 4 elems = 1024 elements per block -> bsum[block]
__global__ __launch_bounds__(256) void block_sums(const int* __restrict__ deg,
                                                  int* __restrict__ bsum, int n) {
  int i0 = blockIdx.x * 1024 + (int)threadIdx.x * 4;
  int s = 0;
  if (i0 + 3 < n) {
    int4 v = *(const int4*)(deg + i0);
    s = v.x + v.y + v.z + v.w;
  } else {
    for (int k = 0; k < 4; k++) if (i0 + k < n) s += deg[i0 + k];
  }
#pragma unroll
  for (int d = 1; d < 64; d <<= 1) s += __shfl_xor(s, d);
  __shared__ int ws[4];
  if ((threadIdx.x & 63) == 0) ws[threadIdx.x >> 6] = s;
  __syncthreads();
  if (threadIdx.x == 0) bsum[blockIdx.x] = ws[0] + ws[1] + ws[2] + ws[3];
}

// single wave scans <=64 block sums -> exclusive tops; writes off[n] = total
__global__ __launch_bounds__(64) void scan_tops(const int* __restrict__ bsum,
                                                int* __restrict__ tops,
                                                int* __restrict__ off, int nb, int n) {
  int l = threadIdx.x;
  int v = (l < nb) ? bsum[l] : 0;
  int s = v;
#pragma unroll
  for (int d = 1; d < 64; d <<= 1) { int t = __shfl_up(s, d); if (l >= d) s += t; }
  if (l < nb) tops[l] = s - v;
  if (l == 63) off[n] = s;
}

__global__ __launch_bounds__(256) void offsets_k(const int* __restrict__ deg,
                                                 const int* __restrict__ tops,
                                                 int* __restrict__ off,
                                                 int* __restrict__ cur, int n) {
  int i0 = blockIdx.x * 1024 + (int)threadIdx.x * 4;
  int4 v = make_int4(0, 0, 0, 0);
  if (i0 + 3 < n) v = *(const int4*)(deg + i0);
  else {
    int t[4] = {0, 0, 0, 0};
    for (int k = 0; k < 4; k++) if (i0 + k < n) t[k] = deg[i0 + k];
    v = make_int4(t[0], t[1], t[2], t[3]);
  }
  int tsum = v.x + v.y + v.z + v.w;
  int l = threadIdx.x & 63, w = threadIdx.x >> 6;
  int si = tsum;
#pragma unroll
  for (int d = 1; d < 64; d <<= 1) { int t = __shfl_up(si, d); if (l >= d) si += t; }
  __shared__ int wsm[4];
  if (l == 63) wsm[w] = si;
  __syncthreads();
  int wpre = 0;
#pragma unroll
  for (int k = 0; k < 4; k++) wpre += (k < w) ? wsm[k] : 0;
  int pre = tops[blockIdx.x] + wpre + (si - tsum);
  int4 o;
  o.x = pre; o.y = o.x + v.x; o.z = o.y + v.y; o.w = o.z + v.z;
  if (i0 + 3 < n) {
    *(int4*)(off + i0) = o;
    *(int4*)(cur + i0) = o;
  } else {
    int oo[4] = {o.x, o.y, o.z, o.w};
    for (int k = 0; k < 4; k++) if (i0 + k < n) { off[i0 + k] = oo[k]; cur[i0 + k] = oo[k]; }
  }
}

__global__ __launch_bounds__(256) void scatter_kernel(const int* __restrict__ src,
                                                      const int* __restrict__ dst,
                                                      int* __restrict__ cur,
                                                      int* __restrict__ csr, int E) {
  int i = blockIdx.x * blockDim.x + threadIdx.x;
  int stride = gridDim.x * blockDim.x;
  for (int e = i; e < E; e += stride) {
    int p = atomicAdd(&cur[dst[e]], 1);
    csr[p] = src[e];
  }
}

// ---------------- MFMA GEMM: out = X(128-row tile) @ W + b ----------------
// grid: ntiles*4 blocks, mat = bid&3 (0=Q,1=K,2=V bf16 out; 3=S f32 out)
// block 256 thr = 4 waves; wave w computes rows [w*32, w*32+32) x 128 cols.
// LDS: As[128][136] bf16 (X tile), Ws[128][136] bf16 (W transposed: [n][k]).

#define LDSP 136

__global__ __launch_bounds__(256) void gemm_qkvs_mfma(
    const float* __restrict__ xin,
    const float* __restrict__ w0, const float* __restrict__ b0,
    const float* __restrict__ w1, const float* __restrict__ b1,
    const float* __restrict__ w2, const float* __restrict__ b2,
    const float* __restrict__ w3, const float* __restrict__ b3,
    ushort_t* __restrict__ Q16, ushort_t* __restrict__ K16,
    ushort_t* __restrict__ V16, float* __restrict__ Sout, int n) {
  extern __shared__ short smem[];
  short* As = smem;              // 128*136
  short* Ws = smem + 128 * LDSP; // 128*136

  const int mat = blockIdx.x & 3;
  const int tile = blockIdx.x >> 2;
  const int row0 = tile * 128;

  const float* wm; const float* bm;
  switch (mat) {
    case 0: wm = w0; bm = b0; break;
    case 1: wm = w1; bm = b1; break;
    case 2: wm = w2; bm = b2; break;
    default: wm = w3; bm = b3; break;
  }

  // stage X tile: f32 -> bf16, row-major [r][k]
  for (int g = threadIdx.x; g < 128 * 32; g += 256) {
    int r = g >> 5, c4 = (g & 31) << 2;
    float4 v = make_float4(0.f, 0.f, 0.f, 0.f);
    if (row0 + r < n) v = *(const float4*)(xin + (size_t)(row0 + r) * D + c4);
    short4 h;
    h.x = (short)f2bf(v.x); h.y = (short)f2bf(v.y);
    h.z = (short)f2bf(v.z); h.w = (short)f2bf(v.w);
    *(short4*)(As + r * LDSP + c4) = h;
  }
  // stage W transposed: Ws[n][k]
  {
    int nidx = threadIdx.x & 127;
    int kph = threadIdx.x >> 7;  // 0..1
#pragma unroll 4
    for (int it = 0; it < 32; ++it) {
      int kp = it * 2 + kph;  // 0..63 (pairs of k)
      float f0 = wm[(2 * kp) * D + nidx];
      float f1 = wm[(2 * kp + 1) * D + nidx];
      uint_t pk = (uint_t)f2bf(f0) | ((uint_t)f2bf(f1) << 16);
      *(uint_t*)(Ws + nidx * LDSP + 2 * kp) = pk;
    }
  }
  __syncthreads();

  const int w = threadIdx.x >> 6;
  const int l = threadIdx.x & 63;
  const int lr = l & 15;
  const int lg = l >> 4;

  f32x4 zero4 = {0.f, 0.f, 0.f, 0.f};
  f32x4 acc[2][8];
#pragma unroll
  for (int i = 0; i < 2; i++)
#pragma unroll
    for (int j = 0; j < 8; j++) acc[i][j] = zero4;

#pragma unroll
  for (int ks = 0; ks < 4; ++ks) {
    int kb = ks * 32 + lg * 8;
    bf16x8 a0 = *(const bf16x8*)(As + (w * 32 + lr) * LDSP + kb);
    bf16x8 a1 = *(const bf16x8*)(As + (w * 32 + 16 + lr) * LDSP + kb);
#pragma unroll
    for (int nc = 0; nc < 8; ++nc) {
      bf16x8 b = *(const bf16x8*)(Ws + (nc * 16 + lr) * LDSP + kb);
      acc[0][nc] = __builtin_amdgcn_mfma_f32_16x16x32_bf16(a0, b, acc[0][nc], 0, 0, 0);
      acc[1][nc] = __builtin_amdgcn_mfma_f32_16x16x32_bf16(a1, b, acc[1][nc], 0, 0, 0);
    }
  }

  // epilogue: D frag row = lg*4 + j, col = lr
  ushort_t* om16 = (mat == 0) ? Q16 : (mat == 1) ? K16 : V16;
#pragma unroll
  for (int mr = 0; mr < 2; ++mr) {
#pragma unroll
    for (int nc = 0; nc < 8; ++nc) {
      int c = nc * 16 + lr;
      float bias = bm[c];
#pragma unroll
      for (int j = 0; j < 4; ++j) {
        int r = row0 + w * 32 + mr * 16 + lg * 4 + j;
        if (r < n) {
          float val = acc[mr][nc][j] + bias;
          if (mat < 3) om16[(size_t)r * D + c] = f2bf(val);
          else Sout[(size_t)r * D + c] = val;
        }
      }
    }
  }
}

// ---------------- per-node edge attention (bf16 gather) ----------------
// 256 thr = 4 nodes/block, one wave per node. thread t(0..63): dims 2t, 2t+1.
// head = t>>4 (dims [32h,32h+32)); dot-reduce over 16 lanes via shfl_xor 1,2,4,8.

__global__ __launch_bounds__(256) void attn_edge64(
    const int* __restrict__ off, const int* __restrict__ csr,
    const ushort_t* __restrict__ Q16, const ushort_t* __restrict__ K16,
    const ushort_t* __restrict__ V16, float* __restrict__ io, int n, int do_relu) {
  const int node = blockIdx.x * 4 + (threadIdx.x >> 6);
  if (node >= n) return;
  const int t = threadIdx.x & 63;
  const int d0 = t * 2;
  const int e0 = off[node];
  const int e1 = off[node + 1];

  // q premultiplied by (1/sqrt(32)) * log2(e) -> logits in log2 domain
  const float QS = 0.25505526f;
  uint_t qb = *(const uint_t*)(Q16 + (size_t)node * D + d0);
  float q0 = bf2f_lo(qb) * QS;
  float q1 = bf2f_hi(qb) * QS;

  float m = -1e30f, s = 0.f, a0 = 0.f, a1 = 0.f;
  int srcN = (e0 < e1) ? csr[e0] : 0;
  for (int e = e0; e < e1; ++e) {
    int src = srcN;
    if (e + 1 < e1) srcN = csr[e + 1];
    uint_t kb = *(const uint_t*)(K16 + (size_t)src * D + d0);
    uint_t vb = *(const uint_t*)(V16 + (size_t)src * D + d0);
    float p = q0 * bf2f_lo(kb) + q1 * bf2f_hi(kb);
    p += __shfl_xor(p, 1);
    p += __shfl_xor(p, 2);
    p += __shfl_xor(p, 4);
    p += __shfl_xor(p, 8);
    float mn = fmaxf(m, p);
    float c = exp2f(m - mn);
    float wgt = exp2f(p - mn);
    s = s * c + wgt;
    a0 = a0 * c + wgt * bf2f_lo(vb);
    a1 = a1 * c + wgt * bf2f_hi(vb);
    m = mn;
  }
  float r = 1.f / (s + 1e-16f);
  float2 sk = *(const float2*)(io + (size_t)node * D + d0);
  float o0 = sk.x + a0 * r;
  float o1 = sk.y + a1 * r;
  if (do_relu) { o0 = fmaxf(o0, 0.f); o1 = fmaxf(o1, 0.f); }
  *(float2*)(io + (size_t)node * D + d0) = make_float2(o0, o1);
}

// ---------------- launch ----------------

extern "C" void kernel_launch(void* const* d_in, const int* in_sizes, int n_in,
                              void* d_out, int out_size, void* d_ws, size_t ws_size,
                              hipStream_t stream) {
  const int N = in_sizes[0] / D;
  const int E = in_sizes[1] / 2;
  const float* x = (const float*)d_in[0];
  const int* ei = (const int*)d_in[1];
  const int* esrc = ei;
  const int* edst = ei + E;

  const float* qw0 = (const float*)d_in[2];  const float* qb0 = (const float*)d_in[3];
  const float* kw0 = (const float*)d_in[4];  const float* kb0 = (const float*)d_in[5];
  const float* vw0 = (const float*)d_in[6];  const float* vb0 = (const float*)d_in[7];
  const float* sw0 = (const float*)d_in[8];  const float* sb0 = (const float*)d_in[9];
  const float* qw1 = (const float*)d_in[10]; const float* qb1 = (const float*)d_in[11];
  const float* kw1 = (const float*)d_in[12]; const float* kb1 = (const float*)d_in[13];
  const float* vw1 = (const float*)d_in[14]; const float* vb1 = (const float*)d_in[15];
  const float* sw1 = (const float*)d_in[16]; const float* sb1 = (const float*)d_in[17];

  float* out = (float*)d_out;

  char* p = (char*)d_ws;
  auto carve = [&](size_t bytes) -> void* {
    void* r = (void*)p;
    p += (bytes + 255) & ~(size_t)255;
    return r;
  };
  int* deg = (int*)carve((size_t)N * 4);
  int* off = (int*)carve((size_t)(N + 1) * 4);
  int* cur = (int*)carve((size_t)N * 4);
  int* csr = (int*)carve((size_t)E * 4);
  int* bsum = (int*)carve(64 * 4);
  int* tops = (int*)carve(64 * 4);
  ushort_t* Q16 = (ushort_t*)carve((size_t)N * D * 2);
  ushort_t* K16 = (ushort_t*)carve((size_t)N * D * 2);
  ushort_t* V16 = (ushort_t*)carve((size_t)N * D * 2);
  float* h1 = (float*)carve((size_t)N * D * 4);

  hipMemsetAsync(deg, 0, (size_t)N * 4, stream);
  int eblocks = (E + 255) / 256;
  int sblocks = (N + 1023) / 1024;  // <= 64 required
  hist_kernel<<<eblocks, 256, 0, stream>>>(edst, deg, E);
  block_sums<<<sblocks, 256, 0, stream>>>(deg, bsum, N);
  scan_tops<<<1, 64, 0, stream>>>(bsum, tops, off, sblocks, N);
  offsets_k<<<sblocks, 256, 0, stream>>>(deg, tops, off, cur, N);
  scatter_kernel<<<eblocks, 256, 0, stream>>>(esrc, edst, cur, csr, E);

  const int ntiles = (N + 127) / 128;
  const int lds_bytes = 2 * 128 * LDSP * 2;  // 69632
  const int agrid = (N + 3) / 4;

  // layer 1
  gemm_qkvs_mfma<<<ntiles * 4, 256, lds_bytes, stream>>>(
      x, qw0, qb0, kw0, kb0, vw0, vb0, sw0, sb0, Q16, K16, V16, h1, N);
  attn_edge64<<<agrid, 256, 0, stream>>>(off, csr, Q16, K16, V16, h1, N, 1);

  // layer 2
  gemm_qkvs_mfma<<<ntiles * 4, 256, lds_bytes, stream>>>(
      h1, qw1, qb1, kw1, kb1, vw1, vb1, sw1, sb1, Q16, K16, V16, out, N);
  attn_edge64<<<agrid, 256, 0, stream>>>(off, csr, Q16, K16, V16, out, N, 0);
}

// Round 3
// 461.503 us; speedup vs baseline: 1.6568x; 1.0498x over previous
//
#include <hip/hip_runtime.h>

#define D 128
#define NHEAD 4
#define DH 32

typedef unsigned short ushort_t;
typedef unsigned int uint_t;
typedef short bf16x8 __attribute__((ext_vector_type(8)));
typedef float f32x4 __attribute__((ext_vector_type(4)));

__device__ inline float bf2f_lo(uint_t u) {
  union { uint_t i; float f; } x; x.i = u << 16; return x.f;
}
__device__ inline float bf2f_hi(uint_t u) {
  union { uint_t i; float f; } x; x.i = u & 0xffff0000u; return x.f;
}
__device__ inline ushort_t f2bf(float f) {
  union { float f; uint_t u; } x; x.f = f;
  return (ushort_t)((x.u + 0x7fffu + ((x.u >> 16) & 1u)) >> 16);
}

// ---------------- CSR build ----------------

__global__ __launch_bounds__(256) void hist_kernel(const int* __restrict__ dst,
                                                   int* __restrict__ deg, int E) {
  int i = blockIdx.x * blockDim.x + threadIdx.x;
  int stride = gridDim.x * blockDim.x;
  for (int e = i; e < E; e += stride) atomicAdd(&deg[dst[e]], 1);
}

// 256 thr x 4 elems = 1024 elements per block -> bsum[block]
__global__ __launch_bounds__(256) void block_sums(const int* __restrict__ deg,
                                                  int* __restrict__ bsum, int n) {
  int i0 = blockIdx.x * 1024 + (int)threadIdx.x * 4;
  int s = 0;
  if (i0 + 3 < n) {
    int4 v = *(const int4*)(deg + i0);
    s = v.x + v.y + v.z + v.w;
  } else {
    for (int k = 0; k < 4; k++) if (i0 + k < n) s += deg[i0 + k];
  }
#pragma unroll
  for (int d = 1; d < 64; d <<= 1) s += __shfl_xor(s, d);
  __shared__ int ws[4];
  if ((threadIdx.x & 63) == 0) ws[threadIdx.x >> 6] = s;
  __syncthreads();
  if (threadIdx.x == 0) bsum[blockIdx.x] = ws[0] + ws[1] + ws[2] + ws[3];
}

// single wave scans <=64 block sums -> exclusive tops; writes off[n] = total
__global__ __launch_bounds__(64) void scan_tops(const int* __restrict__ bsum,
                                                int* __restrict__ tops,
                                                int* __restrict__ off, int nb, int n) {
  int l = threadIdx.x;
  int v = (l < nb) ? bsum[l] : 0;
  int s = v;
#pragma unroll
  for (int d = 1; d < 64; d <<= 1) { int t = __shfl_up(s, d); if (l >= d) s += t; }
  if (l < nb) tops[l] = s - v;
  if (l == 63) off[n] = s;
}

__global__ __launch_bounds__(256) void offsets_k(const int* __restrict__ deg,
                                                 const int* __restrict__ tops,
                                                 int* __restrict__ off,
                                                 int* __restrict__ cur, int n) {
  int i0 = blockIdx.x * 1024 + (int)threadIdx.x * 4;
  int4 v = make_int4(0, 0, 0, 0);
  if (i0 + 3 < n) v = *(const int4*)(deg + i0);
  else {
    int t[4] = {0, 0, 0, 0};
    for (int k = 0; k < 4; k++) if (i0 + k < n) t[k] = deg[i0 + k];
    v = make_int4(t[0], t[1], t[2], t[3]);
  }
  int tsum = v.x + v.y + v.z + v.w;
  int l = threadIdx.x & 63, w = threadIdx.x >> 6;
  int si = tsum;
#pragma unroll
  for (int d = 1; d < 64; d <<= 1) { int t = __shfl_up(si, d); if (l >= d) si += t; }
  __shared__ int wsm[4];
  if (l == 63) wsm[w] = si;
  __syncthreads();
  int wpre = 0;
#pragma unroll
  for (int k = 0; k < 4; k++) wpre += (k < w) ? wsm[k] : 0;
  int pre = tops[blockIdx.x] + wpre + (si - tsum);
  int4 o;
  o.x = pre; o.y = o.x + v.x; o.z = o.y + v.y; o.w = o.z + v.z;
  if (i0 + 3 < n) {
    *(int4*)(off + i0) = o;
    *(int4*)(cur + i0) = o;
  } else {
    int oo[4] = {o.x, o.y, o.z, o.w};
    for (int k = 0; k < 4; k++) if (i0 + k < n) { off[i0 + k] = oo[k]; cur[i0 + k] = oo[k]; }
  }
}

__global__ __launch_bounds__(256) void scatter_kernel(const int* __restrict__ src,
                                                      const int* __restrict__ dst,
                                                      int* __restrict__ cur,
                                                      int* __restrict__ csr, int E) {
  int i = blockIdx.x * blockDim.x + threadIdx.x;
  int stride = gridDim.x * blockDim.x;
  for (int e = i; e < E; e += stride) {
    int p = atomicAdd(&cur[dst[e]], 1);
    csr[p] = src[e];
  }
}

// ---------------- MFMA GEMM: out = X(128-row tile) @ W + b ----------------

#define LDSP 136

__global__ __launch_bounds__(256) void gemm_qkvs_mfma(
    const float* __restrict__ xin,
    const float* __restrict__ w0, const float* __restrict__ b0,
    const float* __restrict__ w1, const float* __restrict__ b1,
    const float* __restrict__ w2, const float* __restrict__ b2,
    const float* __restrict__ w3, const float* __restrict__ b3,
    ushort_t* __restrict__ Q16, ushort_t* __restrict__ K16,
    ushort_t* __restrict__ V16, float* __restrict__ Sout, int n) {
  extern __shared__ short smem[];
  short* As = smem;              // 128*136
  short* Ws = smem + 128 * LDSP; // 128*136

  const int mat = blockIdx.x & 3;
  const int tile = blockIdx.x >> 2;
  const int row0 = tile * 128;

  const float* wm; const float* bm;
  switch (mat) {
    case 0: wm = w0; bm = b0; break;
    case 1: wm = w1; bm = b1; break;
    case 2: wm = w2; bm = b2; break;
    default: wm = w3; bm = b3; break;
  }

  // stage X tile: f32 -> bf16, row-major [r][k]
  for (int g = threadIdx.x; g < 128 * 32; g += 256) {
    int r = g >> 5, c4 = (g & 31) << 2;
    float4 v = make_float4(0.f, 0.f, 0.f, 0.f);
    if (row0 + r < n) v = *(const float4*)(xin + (size_t)(row0 + r) * D + c4);
    short4 h;
    h.x = (short)f2bf(v.x); h.y = (short)f2bf(v.y);
    h.z = (short)f2bf(v.z); h.w = (short)f2bf(v.w);
    *(short4*)(As + r * LDSP + c4) = h;
  }
  // stage W transposed: Ws[n][k]
  {
    int nidx = threadIdx.x & 127;
    int kph = threadIdx.x >> 7;  // 0..1
#pragma unroll 4
    for (int it = 0; it < 32; ++it) {
      int kp = it * 2 + kph;  // 0..63 (pairs of k)
      float f0 = wm[(2 * kp) * D + nidx];
      float f1 = wm[(2 * kp + 1) * D + nidx];
      uint_t pk = (uint_t)f2bf(f0) | ((uint_t)f2bf(f1) << 16);
      *(uint_t*)(Ws + nidx * LDSP + 2 * kp) = pk;
    }
  }
  __syncthreads();

  const int w = threadIdx.x >> 6;
  const int l = threadIdx.x & 63;
  const int lr = l & 15;
  const int lg = l >> 4;

  f32x4 zero4 = {0.f, 0.f, 0.f, 0.f};
  f32x4 acc[2][8];
#pragma unroll
  for (int i = 0; i < 2; i++)
#pragma unroll
    for (int j = 0; j < 8; j++) acc[i][j] = zero4;

#pragma unroll
  for (int ks = 0; ks < 4; ++ks) {
    int kb = ks * 32 + lg * 8;
    bf16x8 a0 = *(const bf16x8*)(As + (w * 32 + lr) * LDSP + kb);
    bf16x8 a1 = *(const bf16x8*)(As + (w * 32 + 16 + lr) * LDSP + kb);
#pragma unroll
    for (int nc = 0; nc < 8; ++nc) {
      bf16x8 b = *(const bf16x8*)(Ws + (nc * 16 + lr) * LDSP + kb);
      acc[0][nc] = __builtin_amdgcn_mfma_f32_16x16x32_bf16(a0, b, acc[0][nc], 0, 0, 0);
      acc[1][nc] = __builtin_amdgcn_mfma_f32_16x16x32_bf16(a1, b, acc[1][nc], 0, 0, 0);
    }
  }

  // epilogue: D frag row = lg*4 + j, col = lr
  ushort_t* om16 = (mat == 0) ? Q16 : (mat == 1) ? K16 : V16;
#pragma unroll
  for (int mr = 0; mr < 2; ++mr) {
#pragma unroll
    for (int nc = 0; nc < 8; ++nc) {
      int c = nc * 16 + lr;
      float bias = bm[c];
#pragma unroll
      for (int j = 0; j < 4; ++j) {
        int r = row0 + w * 32 + mr * 16 + lg * 4 + j;
        if (r < n) {
          float val = acc[mr][nc][j] + bias;
          if (mat < 3) om16[(size_t)r * D + c] = f2bf(val);
          else Sout[(size_t)r * D + c] = val;
        }
      }
    }
  }
}

// ---------------- per-node edge attention: 4 edges / wave-iteration ----------------
// 256 thr = 4 nodes/block, one wave per node.
// lane t: slot g = t&3 (edge), dim-pos l = t>>2 (dims l*8..l*8+7), head = t>>4.
// dot-reduce over dims: shfl_xor 4,8. cross-slot max/sum: shfl_xor 1,2 (quad DPP).

__global__ __launch_bounds__(256) void attn_edge4(
    const int* __restrict__ off, const int* __restrict__ csr,
    const ushort_t* __restrict__ Q16, const ushort_t* __restrict__ K16,
    const ushort_t* __restrict__ V16, float* __restrict__ io, int n, int do_relu) {
  const int node = blockIdx.x * 4 + (threadIdx.x >> 6);
  if (node >= n) return;
  const int t = threadIdx.x & 63;
  const int g = t & 3;
  const int l = t >> 2;
  const int e0 = off[node];
  const int e1 = off[node + 1];

  // q premultiplied by (1/sqrt(32)) * log2(e) -> logits in log2 domain
  const float QS = 0.25505526f;
  uint4 qu = *(const uint4*)(Q16 + (size_t)node * D + l * 8);
  float q[8];
  q[0] = bf2f_lo(qu.x) * QS; q[1] = bf2f_hi(qu.x) * QS;
  q[2] = bf2f_lo(qu.y) * QS; q[3] = bf2f_hi(qu.y) * QS;
  q[4] = bf2f_lo(qu.z) * QS; q[5] = bf2f_hi(qu.z) * QS;
  q[6] = bf2f_lo(qu.w) * QS; q[7] = bf2f_hi(qu.w) * QS;

  float m = -1e30f, s = 0.f;
  float acc[8];
#pragma unroll
  for (int j = 0; j < 8; j++) acc[j] = 0.f;

  for (int base = e0; base < e1; base += 4) {
    int e = base + g;
    bool valid = e < e1;
    int src = valid ? csr[e] : 0;
    const size_t roff = (size_t)src * D + l * 8;
    uint4 ku = *(const uint4*)(K16 + roff);
    uint4 vu = *(const uint4*)(V16 + roff);

    float p = q[0] * bf2f_lo(ku.x);
    p = fmaf(q[1], bf2f_hi(ku.x), p);
    p = fmaf(q[2], bf2f_lo(ku.y), p);
    p = fmaf(q[3], bf2f_hi(ku.y), p);
    p = fmaf(q[4], bf2f_lo(ku.z), p);
    p = fmaf(q[5], bf2f_hi(ku.z), p);
    p = fmaf(q[6], bf2f_lo(ku.w), p);
    p = fmaf(q[7], bf2f_hi(ku.w), p);
    // reduce over dim-lanes (bits 2,3)
    p += __shfl_xor(p, 4);
    p += __shfl_xor(p, 8);
    float logit = valid ? p : -1e30f;

    // max over the 4 slots (bits 0,1)
    float mx = fmaxf(logit, __shfl_xor(logit, 1));
    mx = fmaxf(mx, __shfl_xor(mx, 2));
    float mn = fmaxf(m, mx);
    float c = exp2f(m - mn);
    float wgt = exp2f(logit - mn);
    s = s * c + wgt;

    float vf[8];
    vf[0] = bf2f_lo(vu.x); vf[1] = bf2f_hi(vu.x);
    vf[2] = bf2f_lo(vu.y); vf[3] = bf2f_hi(vu.y);
    vf[4] = bf2f_lo(vu.z); vf[5] = bf2f_hi(vu.z);
    vf[6] = bf2f_lo(vu.w); vf[7] = bf2f_hi(vu.w);
#pragma unroll
    for (int j = 0; j < 8; j++) acc[j] = fmaf(acc[j], c, wgt * vf[j]);
    m = mn;
  }

  // reduce across slots
  s += __shfl_xor(s, 1);
  s += __shfl_xor(s, 2);
#pragma unroll
  for (int j = 0; j < 8; j++) {
    acc[j] += __shfl_xor(acc[j], 1);
    acc[j] += __shfl_xor(acc[j], 2);
  }
  float r = 1.f / (s + 1e-16f);

  if (g == 0) {
    float* op = io + (size_t)node * D + l * 8;
    float4 sk0 = *(const float4*)(op);
    float4 sk1 = *(const float4*)(op + 4);
    float o[8];
    o[0] = sk0.x + acc[0] * r; o[1] = sk0.y + acc[1] * r;
    o[2] = sk0.z + acc[2] * r; o[3] = sk0.w + acc[3] * r;
    o[4] = sk1.x + acc[4] * r; o[5] = sk1.y + acc[5] * r;
    o[6] = sk1.z + acc[6] * r; o[7] = sk1.w + acc[7] * r;
    if (do_relu) {
#pragma unroll
      for (int j = 0; j < 8; j++) o[j] = fmaxf(o[j], 0.f);
    }
    *(float4*)(op) = make_float4(o[0], o[1], o[2], o[3]);
    *(float4*)(op + 4) = make_float4(o[4], o[5], o[6], o[7]);
  }
}

// ---------------- launch ----------------

extern "C" void kernel_launch(void* const* d_in, const int* in_sizes, int n_in,
                              void* d_out, int out_size, void* d_ws, size_t ws_size,
                              hipStream_t stream) {
  const int N = in_sizes[0] / D;
  const int E = in_sizes[1] / 2;
  const float* x = (const float*)d_in[0];
  const int* ei = (const int*)d_in[1];
  const int* esrc = ei;
  const int* edst = ei + E;

  const float* qw0 = (const float*)d_in[2];  const float* qb0 = (const float*)d_in[3];
  const float* kw0 = (const float*)d_in[4];  const float* kb0 = (const float*)d_in[5];
  const float* vw0 = (const float*)d_in[6];  const float* vb0 = (const float*)d_in[7];
  const float* sw0 = (const float*)d_in[8];  const float* sb0 = (const float*)d_in[9];
  const float* qw1 = (const float*)d_in[10]; const float* qb1 = (const float*)d_in[11];
  const float* kw1 = (const float*)d_in[12]; const float* kb1 = (const float*)d_in[13];
  const float* vw1 = (const float*)d_in[14]; const float* vb1 = (const float*)d_in[15];
  const float* sw1 = (const float*)d_in[16]; const float* sb1 = (const float*)d_in[17];

  float* out = (float*)d_out;

  char* p = (char*)d_ws;
  auto carve = [&](size_t bytes) -> void* {
    void* r = (void*)p;
    p += (bytes + 255) & ~(size_t)255;
    return r;
  };
  int* deg = (int*)carve((size_t)N * 4);
  int* off = (int*)carve((size_t)(N + 1) * 4);
  int* cur = (int*)carve((size_t)N * 4);
  int* csr = (int*)carve((size_t)E * 4);
  int* bsum = (int*)carve(64 * 4);
  int* tops = (int*)carve(64 * 4);
  ushort_t* Q16 = (ushort_t*)carve((size_t)N * D * 2);
  ushort_t* K16 = (ushort_t*)carve((size_t)N * D * 2);
  ushort_t* V16 = (ushort_t*)carve((size_t)N * D * 2);
  float* h1 = (float*)carve((size_t)N * D * 4);

  hipMemsetAsync(deg, 0, (size_t)N * 4, stream);
  int eblocks = (E + 255) / 256;
  int sblocks = (N + 1023) / 1024;  // <= 64 required
  hist_kernel<<<eblocks, 256, 0, stream>>>(edst, deg, E);
  block_sums<<<sblocks, 256, 0, stream>>>(deg, bsum, N);
  scan_tops<<<1, 64, 0, stream>>>(bsum, tops, off, sblocks, N);
  offsets_k<<<sblocks, 256, 0, stream>>>(deg, tops, off, cur, N);
  scatter_kernel<<<eblocks, 256, 0, stream>>>(esrc, edst, cur, csr, E);

  const int ntiles = (N + 127) / 128;
  const int lds_bytes = 2 * 128 * LDSP * 2;  // 69632
  const int agrid = (N + 3) / 4;

  // layer 1
  gemm_qkvs_mfma<<<ntiles * 4, 256, lds_bytes, stream>>>(
      x, qw0, qb0, kw0, kb0, vw0, vb0, sw0, sb0, Q16, K16, V16, h1, N);
  attn_edge4<<<agrid, 256, 0, stream>>>(off, csr, Q16, K16, V16, h1, N, 1);

  // layer 2
  gemm_qkvs_mfma<<<ntiles * 4, 256, lds_bytes, stream>>>(
      h1, qw1, qb1, kw1, kb1, vw1, vb1, sw1, sb1, Q16, K16, V16, out, N);
  attn_edge4<<<agrid, 256, 0, stream>>>(off, csr, Q16, K16, V16, out, N, 0);
}